// Round 16
// baseline (109.363 us; speedup 1.0000x reference)
//
#include <hip/hip_runtime.h>

#define NPTS 16384
#define TH 33.33f

typedef __attribute__((ext_vector_type(8)))  __bf16 bf16x8;
typedef __attribute__((ext_vector_type(16))) float  f32x16;

__device__ __forceinline__ unsigned short f2bf(float x) {
    unsigned u = __float_as_uint(x);
    u += 0x7FFFu + ((u >> 16) & 1u);
    return (unsigned short)(u >> 16);
}
__device__ __forceinline__ float bf2f(unsigned short h) {
    return __uint_as_float(((unsigned)h) << 16);
}

union UV { uint4 v; bf16x8 h; unsigned short s[8]; };

// ws: d2part float[4 db][64 rowblock][8 seg][256]  (2 MB) — write-once, no init/atomics.
// fragment map: elem = (g*32 + idx)*8 + j with k = g*8 + j (A/B symmetric, verified R2-R15)
// A k: [qh(3), ql(3), qh(2) | zh, 1,1,1, 0..0]   B k: [ph(3), ph(3), pl(2) | zl, -hp0,-hp1,-hp2, 0..0]
// MFMA score s = qh.ph + ql.ph + qh.pl - hp ~= q.p - hp ;  d^2 = 2*(hq - s)
//
// REGISTER LEDGER at __launch_bounds__(256,4) (128 unified regs/wave): acc 32 + afrag 8 +
// staging 6 + addr ~15. Any change adding >~30 live regs SPILLS (R10/R13/R14).
// SCHEDULING LEDGER: R9 manual pipeline = neutral; R14 full unroll = spill;
// R15 unroll-2 = +50% VALU issue (AGPR<->VGPR copy tax). Keep the R12 loop shape EXACTLY.
// R11: staging ds_write must be lane-consecutive-16B. R13: __shfl on MFMA acc is safe;
// inline asm on MFMA results is NOT (R5/R7 hazard-recognizer bypass).

#define FOLD2(MM, AA) { \
    f32x16 t0 = __builtin_amdgcn_mfma_f32_32x32x16_bf16(AA, q0, zc, 0, 0, 0); \
    f32x16 t1 = __builtin_amdgcn_mfma_f32_32x32x16_bf16(AA, q1, zc, 0, 0, 0); \
    _Pragma("unroll") for (int j = 0; j < 16; j++) MM[j] = fmaxf(fmaxf(t0[j], t1[j]), MM[j]); }

__device__ __forceinline__ void conv_store(unsigned short* lb, int k,
                                           float x, float y, float z) {
    float hp = 0.5f * fmaf(z, z, fmaf(y, y, x * x));
    unsigned short xh = f2bf(x), yh = f2bf(y), zh = f2bf(z);
    unsigned short xl = f2bf(x - bf2f(xh)), yl = f2bf(y - bf2f(yh)), zl = f2bf(z - bf2f(zh));
    float rr = hp;
    unsigned short h0 = f2bf(rr); rr -= bf2f(h0);
    unsigned short h1 = f2bf(rr); rr -= bf2f(h1);
    unsigned short h2 = f2bf(rr);
    UV c0, c1;
    c0.s[0]=xh; c0.s[1]=yh; c0.s[2]=zh; c0.s[3]=xh; c0.s[4]=yh; c0.s[5]=zh; c0.s[6]=xl; c0.s[7]=yl;
    c1.s[0]=zl; c1.s[1]=(unsigned short)(h0^0x8000); c1.s[2]=(unsigned short)(h1^0x8000);
    c1.s[3]=(unsigned short)(h2^0x8000); c1.s[4]=0; c1.s[5]=0; c1.s[6]=0; c1.s[7]=0;
    int t = k >> 5, pos = k & 31;
    *(uint4*)(lb + t * 512 + pos * 8)       = c0.v;   // lanes consecutive-16B: conflict-free
    *(uint4*)(lb + t * 512 + 256 + pos * 8) = c1.v;
}

// hoisted staging: loads issued BEFORE the pt loop (latency covered by folds),
// conversion + LDS write AFTER it. Points k=tid and k=tid+256 per thread.
#define LOAD_PTS(CC) { \
    const float* g0 = pp + (size_t)(seg * 2048 + (CC) * 512 + tid) * 3; \
    px0 = g0[0]; py0 = g0[1]; pz0 = g0[2]; \
    const float* g1 = g0 + 768; \
    px1 = g1[0]; py1 = g1[1]; pz1 = g1[2]; }

#define CONV_WRITE(BUF) { \
    unsigned short* lb = (unsigned short*)(smem + (BUF) * 16384); \
    conv_store(lb, tid,       px0, py0, pz0); \
    conv_store(lb, tid + 256, px1, py1, pz1); }

// shuffle-only epilogue (R13-proven): butterfly row-max within the 32-lane half
// owning the row (C/D map: col = lane&31, row = (j&3)+8*(j>>2)+4*(lane>>5)).
#define EPILOG(MM, HQ, OFF) { \
    _Pragma("unroll") for (int j = 0; j < 16; j++) { \
        float red = MM[j]; \
        red = fmaxf(red, __shfl_xor(red, 1, 64)); \
        red = fmaxf(red, __shfl_xor(red, 2, 64)); \
        red = fmaxf(red, __shfl_xor(red, 4, 64)); \
        red = fmaxf(red, __shfl_xor(red, 8, 64)); \
        red = fmaxf(red, __shfl_xor(red, 16, 64)); \
        int r0 = (j & 3) + 8 * (j >> 2) + 4 * g; \
        float hqr = __shfl(HQ, r0, 64); \
        if (cc == j) { \
            float d2 = 2.0f * (hqr - red); \
            float d = fminf(sqrtf(fmaxf(d2, 0.0f)), TH); \
            dst[wave * 64 + (OFF) + r0] = d; } } }

__global__ __launch_bounds__(256, 4) void chamfer_kernel(
        const float* __restrict__ src, const float* __restrict__ tgt,
        float* __restrict__ d2part, float* __restrict__ out)
{
    const int db = blockIdx.y, dir = db >> 1, b = db & 1;
    const int rowblock = blockIdx.x >> 3, seg = blockIdx.x & 7;   // 64 rowblocks x 8 segs
    const int tid = threadIdx.x, wave = tid >> 6, lane = tid & 63;
    const int g = lane >> 5, cc = lane & 31;
    if (blockIdx.x == 0 && db == 0 && tid < 2) out[tid] = 0.0f;   // replaces memset node
    const float* qp = (dir == 0 ? src : tgt) + (size_t)b * NPTS * 3;
    const float* pp = (dir == 0 ? tgt : src) + (size_t)b * NPTS * 3;
    const unsigned short one = 0x3F80;

    __shared__ alignas(16) unsigned char smem[32768];   // 2 x 16 KB stage buffers

    // ---- A fragments + hq: 2 row-tiles (64 rows) per wave ----
    const int rt0 = rowblock * 8 + wave * 2;
    bf16x8 afrag[2]; float hq[2];
#pragma unroll
    for (int i = 0; i < 2; i++) {
        int r = (rt0 + i) * 32 + cc;
        float x = qp[r * 3 + 0], y = qp[r * 3 + 1], z = qp[r * 3 + 2];
        hq[i] = 0.5f * fmaf(z, z, fmaf(y, y, x * x));
        unsigned short xh = f2bf(x), yh = f2bf(y), zh = f2bf(z);
        unsigned short xl = f2bf(x - bf2f(xh)), yl = f2bf(y - bf2f(yh)), zl = f2bf(z - bf2f(zh));
        UV f0, f1, rv;
        f0.s[0]=xh; f0.s[1]=yh; f0.s[2]=zh; f0.s[3]=xl; f0.s[4]=yl; f0.s[5]=zl; f0.s[6]=xh; f0.s[7]=yh;
        f1.s[0]=zh; f1.s[1]=one; f1.s[2]=one; f1.s[3]=one; f1.s[4]=0; f1.s[5]=0; f1.s[6]=0; f1.s[7]=0;
        rv.v = g ? f1.v : f0.v;
        afrag[i] = rv.h;
    }

    f32x16 m0 = -3.0e38f, m1 = -3.0e38f;
    const f32x16 zc = 0.0f;
    float px0, py0, pz0, px1, py1, pz1;

    LOAD_PTS(0)
    CONV_WRITE(0)
    __syncthreads();
#pragma unroll 1
    for (int c = 0; c < 4; ++c) {                 // 4 chunks x 16 col-tiles
        if (c < 3) LOAD_PTS(c + 1)                // issue loads; consumed after pt loop
        const unsigned short* bb = (const unsigned short*)(smem + (c & 1) * 16384);
#pragma unroll 1
        for (int pt = 0; pt < 8; ++pt) {          // 2 col-tiles per iter (R12 shape: no unroll)
            bf16x8 q0 = *(const bf16x8*)(bb + pt * 1024 + lane * 8);
            bf16x8 q1 = *(const bf16x8*)(bb + pt * 1024 + 512 + lane * 8);
            FOLD2(m0, afrag[0])
            FOLD2(m1, afrag[1])
        }
        if (c < 3) CONV_WRITE((c + 1) & 1)        // convert + stage after latency is hidden
        __syncthreads();
    }

    float* dst = d2part + (((size_t)(db * 64 + rowblock)) * 8 + seg) * 256;
    EPILOG(m0, hq[0], 0)
    EPILOG(m1, hq[1], 32)
}

__global__ __launch_bounds__(256) void merge_kernel(const float* __restrict__ d2part,
                                                    float* __restrict__ out) {
    const int b = blockIdx.y;                     // batch
    const int slice = blockIdx.x;                 // 16 slices of 1024 rows
    const int tid = threadIdx.x;
    float s = 0.0f;
#pragma unroll
    for (int pass = 0; pass < 2; pass++) {        // dir 0 and dir 1
        const float* base = d2part + (size_t)(pass * 2 + b) * 64 * 8 * 256;
#pragma unroll
        for (int i = 0; i < 4; i++) {
            int r = slice * 1024 + i * 256 + tid;
            const float* p = base + (size_t)(r >> 8) * 2048 + (r & 255);
            float m = p[0];
#pragma unroll
            for (int sgi = 1; sgi < 8; sgi++) m = fminf(m, p[sgi * 256]);
            s += m;
        }
    }
#pragma unroll
    for (int off = 32; off > 0; off >>= 1) s += __shfl_down(s, off, 64);
    __shared__ float w[4];
    if ((tid & 63) == 0) w[tid >> 6] = s;
    __syncthreads();
    if (tid == 0) {
        float t = (w[0] + w[1]) + (w[2] + w[3]);
        atomicAdd(&out[b], t * (1.0f / (2.0f * NPTS)));  // (mean_fwd + mean_bwd) / 2
    }
}

extern "C" void kernel_launch(void* const* d_in, const int* in_sizes, int n_in,
                              void* d_out, int out_size, void* d_ws, size_t ws_size,
                              hipStream_t stream) {
    const float* src = (const float*)d_in[0];
    const float* tgt = (const float*)d_in[1];
    float* out = (float*)d_out;
    float* d2part = (float*)d_ws;                 // 2 MB, write-once (no init needed)

    chamfer_kernel<<<dim3(512, 4), 256, 0, stream>>>(src, tgt, d2part, out);
    merge_kernel<<<dim3(16, 2), 256, 0, stream>>>(d2part, out);
}

// Round 17
// 91.063 us; speedup vs baseline: 1.2010x; 1.2010x over previous
//
#include <hip/hip_runtime.h>

#define NPTS 16384
#define TH 33.33f

typedef __attribute__((ext_vector_type(8)))  __bf16 bf16x8;
typedef __attribute__((ext_vector_type(16))) float  f32x16;

__device__ __forceinline__ unsigned short f2bf(float x) {
    unsigned u = __float_as_uint(x);
    u += 0x7FFFu + ((u >> 16) & 1u);
    return (unsigned short)(u >> 16);
}
__device__ __forceinline__ float bf2f(unsigned short h) {
    return __uint_as_float(((unsigned)h) << 16);
}

union UV { uint4 v; bf16x8 h; unsigned short s[8]; };

// ws: d2part float[4 db][64 rowblock][8 seg][256]  (2 MB) — write-once, no init/atomics.
// fragment map: elem = (g*32 + idx)*8 + j with k = g*8 + j (A/B symmetric, verified R2-R16)
// A k: [qh(3), ql(3), qh(2) | zh, 1,1,1, 0..0]   B k: [ph(3), ph(3), pl(2) | zl, -hp0,-hp1,-hp2, 0..0]
// MFMA score s = qh.ph + ql.ph + qh.pl - hp ~= q.p - hp ;  d^2 = 2*(hq - s)
//
// === FROZEN CHAMPION (R12): every deviation regressed ===
// REGISTER LEDGER at (256,4) (128 unified regs/wave): acc 32 + afrag 8 + staging 6 +
//   addr ~15. Adding >~30 live regs SPILLS (R10: 4 row-tiles; R13: (256,8); R14: full unroll).
// SCHEDULING LEDGER: R9 manual pipeline = neutral; R14 full unroll = spill; R15 unroll-2 and
//   R16 shuffle-epilogue = +14 us VALU (AGPR<->VGPR copy tax — __shfl needs VGPR operands,
//   forcing acc layout copies in the MAIN LOOP). Keep LDS-scratch epilogue + unroll 1.
// R11: staging ds_write must be lane-consecutive-16B. R5/R7: no inline asm on MFMA results.

#define FOLD2(MM, AA) { \
    f32x16 t0 = __builtin_amdgcn_mfma_f32_32x32x16_bf16(AA, q0, zc, 0, 0, 0); \
    f32x16 t1 = __builtin_amdgcn_mfma_f32_32x32x16_bf16(AA, q1, zc, 0, 0, 0); \
    _Pragma("unroll") for (int j = 0; j < 16; j++) MM[j] = fmaxf(fmaxf(t0[j], t1[j]), MM[j]); }

__device__ __forceinline__ void conv_store(unsigned short* lb, int k,
                                           float x, float y, float z) {
    float hp = 0.5f * fmaf(z, z, fmaf(y, y, x * x));
    unsigned short xh = f2bf(x), yh = f2bf(y), zh = f2bf(z);
    unsigned short xl = f2bf(x - bf2f(xh)), yl = f2bf(y - bf2f(yh)), zl = f2bf(z - bf2f(zh));
    float rr = hp;
    unsigned short h0 = f2bf(rr); rr -= bf2f(h0);
    unsigned short h1 = f2bf(rr); rr -= bf2f(h1);
    unsigned short h2 = f2bf(rr);
    UV c0, c1;
    c0.s[0]=xh; c0.s[1]=yh; c0.s[2]=zh; c0.s[3]=xh; c0.s[4]=yh; c0.s[5]=zh; c0.s[6]=xl; c0.s[7]=yl;
    c1.s[0]=zl; c1.s[1]=(unsigned short)(h0^0x8000); c1.s[2]=(unsigned short)(h1^0x8000);
    c1.s[3]=(unsigned short)(h2^0x8000); c1.s[4]=0; c1.s[5]=0; c1.s[6]=0; c1.s[7]=0;
    int t = k >> 5, pos = k & 31;
    *(uint4*)(lb + t * 512 + pos * 8)       = c0.v;   // lanes consecutive-16B: conflict-free
    *(uint4*)(lb + t * 512 + 256 + pos * 8) = c1.v;
}

// hoisted staging: loads issued BEFORE the pt loop (latency covered by folds),
// conversion + LDS write AFTER it. Points k=tid and k=tid+256 per thread.
#define LOAD_PTS(CC) { \
    const float* g0 = pp + (size_t)(seg * 2048 + (CC) * 512 + tid) * 3; \
    px0 = g0[0]; py0 = g0[1]; pz0 = g0[2]; \
    const float* g1 = g0 + 768; \
    px1 = g1[0]; py1 = g1[1]; pz1 = g1[2]; }

#define CONV_WRITE(BUF) { \
    unsigned short* lb = (unsigned short*)(smem + (BUF) * 16384); \
    conv_store(lb, tid,       px0, py0, pz0); \
    conv_store(lb, tid + 256, px1, py1, pz1); }

// LDS-scratch epilogue (R12 champion form): acc -> padded LDS -> per-lane row reduce.
#define EPILOG(MM, P) { \
    float* sc = scratch + wave * 1056; \
    _Pragma("unroll") for (int j = 0; j < 16; j++) { \
        int r0 = (j & 3) + 8 * (j >> 2) + 4 * g; sc[r0 * 33 + cc] = MM[j]; } \
    __syncthreads(); \
    const float* sr = sc + cc * 33 + g * 16; \
    float mx = -3.0e38f; \
    _Pragma("unroll") for (int k = 0; k < 16; k++) mx = fmaxf(mx, sr[k]); \
    mx = fmaxf(mx, __shfl_xor(mx, 32, 64)); \
    if (lane < 32) { \
        float d2 = 2.0f * (hq[P] - mx); \
        float d = fminf(sqrtf(fmaxf(d2, 0.0f)), TH); \
        dst[wave * 64 + (P) * 32 + lane] = d; } \
    __syncthreads(); }

__global__ __launch_bounds__(256, 4) void chamfer_kernel(
        const float* __restrict__ src, const float* __restrict__ tgt,
        float* __restrict__ d2part, float* __restrict__ out)
{
    const int db = blockIdx.y, dir = db >> 1, b = db & 1;
    const int rowblock = blockIdx.x >> 3, seg = blockIdx.x & 7;   // 64 rowblocks x 8 segs
    const int tid = threadIdx.x, wave = tid >> 6, lane = tid & 63;
    const int g = lane >> 5, cc = lane & 31;
    if (blockIdx.x == 0 && db == 0 && tid < 2) out[tid] = 0.0f;   // replaces memset node
    const float* qp = (dir == 0 ? src : tgt) + (size_t)b * NPTS * 3;
    const float* pp = (dir == 0 ? tgt : src) + (size_t)b * NPTS * 3;
    const unsigned short one = 0x3F80;

    // 32 KB: two 16 KB stage buffers; aliased as epilogue scratch after the loop
    __shared__ alignas(16) unsigned char smem[32768];
    float* scratch = (float*)smem;   // 4 waves * 32 rows * 33 floats = 16.9 KB

    // ---- A fragments + hq: 2 row-tiles (64 rows) per wave ----
    const int rt0 = rowblock * 8 + wave * 2;
    bf16x8 afrag[2]; float hq[2];
#pragma unroll
    for (int i = 0; i < 2; i++) {
        int r = (rt0 + i) * 32 + cc;
        float x = qp[r * 3 + 0], y = qp[r * 3 + 1], z = qp[r * 3 + 2];
        hq[i] = 0.5f * fmaf(z, z, fmaf(y, y, x * x));
        unsigned short xh = f2bf(x), yh = f2bf(y), zh = f2bf(z);
        unsigned short xl = f2bf(x - bf2f(xh)), yl = f2bf(y - bf2f(yh)), zl = f2bf(z - bf2f(zh));
        UV f0, f1, rv;
        f0.s[0]=xh; f0.s[1]=yh; f0.s[2]=zh; f0.s[3]=xl; f0.s[4]=yl; f0.s[5]=zl; f0.s[6]=xh; f0.s[7]=yh;
        f1.s[0]=zh; f1.s[1]=one; f1.s[2]=one; f1.s[3]=one; f1.s[4]=0; f1.s[5]=0; f1.s[6]=0; f1.s[7]=0;
        rv.v = g ? f1.v : f0.v;
        afrag[i] = rv.h;
    }

    f32x16 m0 = -3.0e38f, m1 = -3.0e38f;
    const f32x16 zc = 0.0f;
    float px0, py0, pz0, px1, py1, pz1;

    LOAD_PTS(0)
    CONV_WRITE(0)
    __syncthreads();
#pragma unroll 1
    for (int c = 0; c < 4; ++c) {                 // 4 chunks x 16 col-tiles
        if (c < 3) LOAD_PTS(c + 1)                // issue loads; consumed after pt loop
        const unsigned short* bb = (const unsigned short*)(smem + (c & 1) * 16384);
#pragma unroll 1
        for (int pt = 0; pt < 8; ++pt) {          // 2 col-tiles per iter (champion shape)
            bf16x8 q0 = *(const bf16x8*)(bb + pt * 1024 + lane * 8);
            bf16x8 q1 = *(const bf16x8*)(bb + pt * 1024 + 512 + lane * 8);
            FOLD2(m0, afrag[0])
            FOLD2(m1, afrag[1])
        }
        if (c < 3) CONV_WRITE((c + 1) & 1)        // convert + stage after latency is hidden
        __syncthreads();
    }

    float* dst = d2part + (((size_t)(db * 64 + rowblock)) * 8 + seg) * 256;
    EPILOG(m0, 0)
    EPILOG(m1, 1)
}

__global__ __launch_bounds__(256) void merge_kernel(const float* __restrict__ d2part,
                                                    float* __restrict__ out) {
    const int b = blockIdx.y;                     // batch
    const int slice = blockIdx.x;                 // 16 slices of 1024 rows
    const int tid = threadIdx.x;
    float s = 0.0f;
#pragma unroll
    for (int pass = 0; pass < 2; pass++) {        // dir 0 and dir 1
        const float* base = d2part + (size_t)(pass * 2 + b) * 64 * 8 * 256;
#pragma unroll
        for (int i = 0; i < 4; i++) {
            int r = slice * 1024 + i * 256 + tid;
            const float* p = base + (size_t)(r >> 8) * 2048 + (r & 255);
            float m = p[0];
#pragma unroll
            for (int sgi = 1; sgi < 8; sgi++) m = fminf(m, p[sgi * 256]);
            s += m;
        }
    }
#pragma unroll
    for (int off = 32; off > 0; off >>= 1) s += __shfl_down(s, off, 64);
    __shared__ float w[4];
    if ((tid & 63) == 0) w[tid >> 6] = s;
    __syncthreads();
    if (tid == 0) {
        float t = (w[0] + w[1]) + (w[2] + w[3]);
        atomicAdd(&out[b], t * (1.0f / (2.0f * NPTS)));  // (mean_fwd + mean_bwd) / 2
    }
}

extern "C" void kernel_launch(void* const* d_in, const int* in_sizes, int n_in,
                              void* d_out, int out_size, void* d_ws, size_t ws_size,
                              hipStream_t stream) {
    const float* src = (const float*)d_in[0];
    const float* tgt = (const float*)d_in[1];
    float* out = (float*)d_out;
    float* d2part = (float*)d_ws;                 // 2 MB, write-once (no init needed)

    chamfer_kernel<<<dim3(512, 4), 256, 0, stream>>>(src, tgt, d2part, out);
    merge_kernel<<<dim3(16, 2), 256, 0, stream>>>(d2part, out);
}